// Round 1
// baseline (611.330 us; speedup 1.0000x reference)
//
#include <hip/hip_runtime.h>
#include <hip/hip_bf16.h>

// Problem constants
#define B_   64
#define S_   512
#define L_   256
#define D_   768
#define RED_ 400
#define HID_ 100
#define TAGS_ 5
#define POL_ 4
#define BL_  (B_ * L_)   // 16384

// ---------------------------------------------------------------------------
// 1) Segment mean: pooled[b,l,:] = mean(bert[b, start..end, :]), len in {1,2}
// ---------------------------------------------------------------------------
__global__ __launch_bounds__(256) void seg_mean_kernel(
    const float* __restrict__ bert, const int* __restrict__ pos,
    float* __restrict__ pooled)
{
    int bl = blockIdx.x;               // 0..16383
    int b  = bl >> 8;                  // /L_
    int s  = pos[bl * 2 + 0];
    int e  = pos[bl * 2 + 1];
    int len = e - s + 1;               // 1 or 2
    const float* v0 = bert + ((size_t)b * S_ + s) * D_;
    float inv = (len == 2) ? 0.5f : 1.0f;
    float* out = pooled + (size_t)bl * D_;
    for (int d = threadIdx.x; d < D_; d += 256) {
        float x = v0[d];
        if (len == 2) x += v0[D_ + d];
        out[d] = x * inv;
    }
}

// ---------------------------------------------------------------------------
// 2) Generic tiled f32 GEMM: C[M,N] = act(A[M,K] @ B[K,N] + bias[N])
//    A row-major (lda=K), B row-major with leading dim ldb.
//    BM=BN=64, BK=16, 256 threads, 4x4 micro-tile. M must be multiple of 64.
// ---------------------------------------------------------------------------
template <bool RELU>
__global__ __launch_bounds__(256) void gemm_bias_kernel(
    const float* __restrict__ A, const float* __restrict__ B,
    const float* __restrict__ bias, float* __restrict__ C,
    int M, int N, int K, int ldb)
{
    __shared__ float As[16][64 + 1];
    __shared__ float Bs[16][64 + 1];

    const int tid = threadIdx.x;
    const int bm = blockIdx.x * 64;
    const int bn = blockIdx.y * 64;
    const int tx = tid & 15;
    const int ty = tid >> 4;

    float acc[4][4] = {};

    for (int k0 = 0; k0 < K; k0 += 16) {
        // Load A tile 64x16 (transposed into As[k][m])
        {
            int m  = tid >> 2;            // 0..63
            int kb = (tid & 3) * 4;       // 0,4,8,12
            const float* Ap = A + (size_t)(bm + m) * K + k0 + kb;
            #pragma unroll
            for (int i = 0; i < 4; ++i) {
                int k = k0 + kb + i;
                As[kb + i][m] = (k < K) ? Ap[i] : 0.f;
            }
        }
        // Load B tile 16x64
        {
            int n  = tid & 63;
            int kr = tid >> 6;            // 0..3
            #pragma unroll
            for (int p = 0; p < 4; ++p) {
                int k = k0 + kr + p * 4;
                float v = 0.f;
                if (k < K && (bn + n) < N) v = B[(size_t)k * ldb + bn + n];
                Bs[kr + p * 4][n] = v;
            }
        }
        __syncthreads();

        #pragma unroll
        for (int k = 0; k < 16; ++k) {
            float a[4], b[4];
            #pragma unroll
            for (int i = 0; i < 4; ++i) a[i] = As[k][ty * 4 + i];
            #pragma unroll
            for (int j = 0; j < 4; ++j) b[j] = Bs[k][tx * 4 + j];
            #pragma unroll
            for (int i = 0; i < 4; ++i)
                #pragma unroll
                for (int j = 0; j < 4; ++j)
                    acc[i][j] += a[i] * b[j];
        }
        __syncthreads();
    }

    #pragma unroll
    for (int i = 0; i < 4; ++i) {
        int m = bm + ty * 4 + i;
        #pragma unroll
        for (int j = 0; j < 4; ++j) {
            int n = bn + tx * 4 + j;
            if (n < N) {
                float v = acc[i][j] + bias[n];
                if (RELU) v = fmaxf(v, 0.f);
                C[(size_t)m * N + n] = v;
            }
        }
    }
}

// ---------------------------------------------------------------------------
// 3) Tag heads: ap_out = ap @ W_ap_tag + b ; op_out = op @ W_op_tag + b
//    out layout: [ap_out (81920) | op_out (81920)]
// ---------------------------------------------------------------------------
__global__ __launch_bounds__(256) void tag_kernel(
    const float* __restrict__ ap, const float* __restrict__ op,
    const float* __restrict__ Wap, const float* __restrict__ bap,
    const float* __restrict__ Wop, const float* __restrict__ bop,
    float* __restrict__ out)
{
    int idx = blockIdx.x * 256 + threadIdx.x;     // 0..163839
    if (idx >= 2 * BL_ * TAGS_) return;
    int half = idx / (BL_ * TAGS_);
    int r    = idx % (BL_ * TAGS_);
    int row  = r / TAGS_;
    int t    = r % TAGS_;
    const float* x = (half ? op : ap) + (size_t)row * HID_;
    const float* W = half ? Wop : Wap;
    float s = (half ? bop : bap)[t];
    #pragma unroll 4
    for (int k = 0; k < HID_; ++k) s += x[k] * W[k * TAGS_ + t];
    out[idx] = s;
}

// ---------------------------------------------------------------------------
// 4) Triplet: per-batch C[j, ip] = sum_h op[b,j,h] * affine[b,ip,h]
//    affine viewed as [1024,100] rows ip = i*4+p (contiguous with reshape).
//    Output triplet[b,j,i,p] = out[b*262144 + j*1024 + ip].
//    64x64 tiles of (j, ip), K=100 fully staged in LDS.
// ---------------------------------------------------------------------------
__global__ __launch_bounds__(256) void triplet_kernel(
    const float* __restrict__ op, const float* __restrict__ affine,
    float* __restrict__ out)
{
    __shared__ float As[64][101];   // op rows (j)
    __shared__ float Bs[64][101];   // affine rows (ip)

    const int b   = blockIdx.z;
    const int j0  = blockIdx.x * 64;
    const int ip0 = blockIdx.y * 64;

    const float* A  = op     + (size_t)b * L_ * HID_;          // [256,100]
    const float* Bm = affine + (size_t)b * (L_ * POL_) * HID_; // [1024,100]

    const int tid = threadIdx.x;
    for (int idx = tid; idx < 64 * HID_; idx += 256) {
        int r = idx / HID_;
        int c = idx - r * HID_;
        As[r][c] = A[(size_t)(j0 + r) * HID_ + c];
        Bs[r][c] = Bm[(size_t)(ip0 + r) * HID_ + c];
    }
    __syncthreads();

    const int tx = tid & 15;
    const int ty = tid >> 4;
    float acc[4][4] = {};

    for (int k = 0; k < HID_; ++k) {
        float a[4], bb[4];
        #pragma unroll
        for (int i = 0; i < 4; ++i) a[i]  = As[ty * 4 + i][k];
        #pragma unroll
        for (int j = 0; j < 4; ++j) bb[j] = Bs[tx * 4 + j][k];
        #pragma unroll
        for (int i = 0; i < 4; ++i)
            #pragma unroll
            for (int j = 0; j < 4; ++j)
                acc[i][j] += a[i] * bb[j];
    }

    float* O = out + ((size_t)b * L_ + j0) * (L_ * POL_) + ip0;
    #pragma unroll
    for (int i = 0; i < 4; ++i)
        #pragma unroll
        for (int j = 0; j < 4; ++j)
            O[(size_t)(ty * 4 + i) * (L_ * POL_) + tx * 4 + j] = acc[i][j];
}

// ---------------------------------------------------------------------------
extern "C" void kernel_launch(void* const* d_in, const int* in_sizes, int n_in,
                              void* d_out, int out_size, void* d_ws, size_t ws_size,
                              hipStream_t stream)
{
    const float* bert    = (const float*)d_in[0];
    const int*   pos     = (const int*)  d_in[1];
    const float* W_reduc = (const float*)d_in[2];
    const float* b_reduc = (const float*)d_in[3];
    const float* W_ap    = (const float*)d_in[4];
    const float* b_ap    = (const float*)d_in[5];
    const float* W_op    = (const float*)d_in[6];
    const float* b_op    = (const float*)d_in[7];
    const float* W_ap_tag= (const float*)d_in[8];
    const float* b_ap_tag= (const float*)d_in[9];
    const float* W_op_tag= (const float*)d_in[10];
    const float* b_op_tag= (const float*)d_in[11];
    const float* W_bi    = (const float*)d_in[12];

    float* out = (float*)d_out;

    // Workspace layout (floats)
    float* ws      = (float*)d_ws;
    float* pooled  = ws;                                // 16384*768
    float* h       = pooled + (size_t)BL_ * D_;         // 16384*400
    float* ap      = h      + (size_t)BL_ * RED_;       // 16384*100
    float* opv     = ap     + (size_t)BL_ * HID_;       // 16384*100
    float* affine  = opv    + (size_t)BL_ * HID_;       // 16384*400

    // 1) segment mean
    seg_mean_kernel<<<BL_, 256, 0, stream>>>(bert, pos, pooled);

    // 2) h = relu(pooled @ W_reduc + b_reduc)   [16384,768]x[768,400]
    gemm_bias_kernel<true><<<dim3(BL_ / 64, (RED_ + 63) / 64), 256, 0, stream>>>(
        pooled, W_reduc, b_reduc, h, BL_, RED_, D_, RED_);

    // 3) ap = relu(h @ W_ap + b_ap); op = relu(h @ W_op + b_op)
    gemm_bias_kernel<true><<<dim3(BL_ / 64, (HID_ + 63) / 64), 256, 0, stream>>>(
        h, W_ap, b_ap, ap, BL_, HID_, RED_, HID_);
    gemm_bias_kernel<true><<<dim3(BL_ / 64, (HID_ + 63) / 64), 256, 0, stream>>>(
        h, W_op, b_op, opv, BL_, HID_, RED_, HID_);

    // 4) affine = ap @ W_bi[0:100,:] + W_bi[100,:]   [16384,100]x[100,400]
    gemm_bias_kernel<false><<<dim3(BL_ / 64, (RED_ + 63) / 64), 256, 0, stream>>>(
        ap, W_bi, W_bi + (size_t)HID_ * RED_, affine, BL_, RED_, HID_, RED_);

    // 5) tag heads -> out[0 : 163840]
    tag_kernel<<<(2 * BL_ * TAGS_ + 255) / 256, 256, 0, stream>>>(
        ap, opv, W_ap_tag, b_ap_tag, W_op_tag, b_op_tag, out);

    // 6) triplet -> out[163840 : ]
    triplet_kernel<<<dim3(L_ / 64, (L_ * POL_) / 64, B_), 256, 0, stream>>>(
        opv, affine, out + 2 * BL_ * TAGS_);
}

// Round 2
// 121.736 us; speedup vs baseline: 5.0218x; 5.0218x over previous
//
#include <hip/hip_runtime.h>
#include <hip/hip_bf16.h>

// Problem constants
#define B_    64
#define S_    512
#define L_    256
#define D_    768      // K of GEMM1 (multiple of 32)
#define RED_  400
#define REDP_ 512      // padded N of GEMM1 / K of GEMM2-3
#define HID_  100
#define HIDP_ 128      // padded N of GEMM2-3 / K of affine+triplet
#define TAGS_ 5
#define POL_  4
#define NBI_  512      // padded N of affine GEMM (4 * 128)
#define BL_   (B_ * L_)  // 16384

typedef __attribute__((ext_vector_type(8))) short short8;
typedef __attribute__((ext_vector_type(4))) float f32x4;

#define GLOAD_LDS16(gp, lp) __builtin_amdgcn_global_load_lds( \
    (const __attribute__((address_space(1))) void*)(gp),      \
    (__attribute__((address_space(3))) void*)(lp), 16, 0, 0)

// ---------------------------------------------------------------------------
// 1) Segment mean -> bf16 pooled [BL, 768]
// ---------------------------------------------------------------------------
__global__ __launch_bounds__(256) void seg_mean_kernel(
    const float* __restrict__ bert, const int* __restrict__ pos,
    __hip_bfloat16* __restrict__ pooled)
{
    int bl = blockIdx.x;
    int b  = bl >> 8;
    int s  = pos[bl * 2 + 0];
    int e  = pos[bl * 2 + 1];
    int len = e - s + 1;
    const float* v0 = bert + ((size_t)b * S_ + s) * D_;
    float inv = (len == 2) ? 0.5f : 1.0f;
    __hip_bfloat16* out = pooled + (size_t)bl * D_;
    for (int d = threadIdx.x; d < D_; d += 256) {
        float x = v0[d];
        if (len == 2) x += v0[D_ + d];
        out[d] = __float2bfloat16(x * inv);
    }
}

// ---------------------------------------------------------------------------
// Weight prep: Wt[n*Kp + k] = bf16( (k<K && n<N) ? W[k*ldw + n] : 0 )
// ---------------------------------------------------------------------------
__global__ __launch_bounds__(256) void prep_wt_kernel(
    const float* __restrict__ W, int ldw, int K, int N,
    __hip_bfloat16* __restrict__ Wt, int Kp, int Np)
{
    int idx = blockIdx.x * 256 + threadIdx.x;
    if (idx >= Np * Kp) return;
    int n = idx / Kp;
    int k = idx - n * Kp;
    float v = (n < N && k < K) ? W[(size_t)k * ldw + n] : 0.f;
    Wt[idx] = __float2bfloat16(v);
}

// W_bi [101][400]; affine output col n = p*128 + h  <->  orig col p*100 + h.
// Wt [512][128] (K=100 padded to 128); bias[n] from W_bi row 100.
__global__ __launch_bounds__(256) void prep_wtbi_kernel(
    const float* __restrict__ Wbi, __hip_bfloat16* __restrict__ Wt,
    float* __restrict__ biasp)
{
    int idx = blockIdx.x * 256 + threadIdx.x;
    if (idx >= NBI_ * HIDP_) return;
    int n = idx >> 7;         // 0..511
    int k = idx & 127;
    int p = n >> 7;
    int h = n & 127;
    float v = 0.f;
    if (h < HID_ && k < HID_) v = Wbi[(size_t)k * RED_ + p * HID_ + h];
    Wt[idx] = __float2bfloat16(v);
    if (k == 0) biasp[n] = (h < HID_) ? Wbi[(size_t)HID_ * RED_ + p * HID_ + h] : 0.f;
}

__global__ __launch_bounds__(256) void prep_bias_kernel(
    const float* __restrict__ b, int N, float* __restrict__ bp, int Np)
{
    int n = blockIdx.x * 256 + threadIdx.x;
    if (n < Np) bp[n] = (n < N) ? b[n] : 0.f;
}

// ---------------------------------------------------------------------------
// MFMA GEMM: C[M,N] = act(A[M,K] @ Bt[N,K]^T + bias[N])
// A,Bt bf16 row-major; M%128==0, N%128==0, K%32==0.
// 128x128 tile, BK=32, 4 waves (2x2), each wave 64x64 (4x4 frags 16x16x32).
// Double-buffered LDS, staged with global_load_lds width 16.
// ---------------------------------------------------------------------------
template <bool RELU, bool STORE_BF16>
__global__ __launch_bounds__(256) void gemm_mfma_kernel(
    const short* __restrict__ A, const short* __restrict__ Bt,
    const float* __restrict__ bias, void* __restrict__ Cout,
    int M, int N, int K)
{
    __shared__ __align__(16) short lds[2][8192];   // [buf][A 4096 | B 4096]

    const int t  = threadIdx.x;
    const int wv = t >> 6;
    const int ln = t & 63;
    const int wm = wv >> 1;        // 0..1
    const int wn = wv & 1;         // 0..1
    const int bm = blockIdx.x * 128;
    const int bn = blockIdx.y * 128;

    const int srow = t >> 2;       // 0..63 staging row within chunk
    const int skc  = (t & 3) * 8;  // staging k offset (shorts)

    f32x4 acc[4][4] = {};

    const int NT = K >> 5;

    // prologue stage k-tile 0 into buf 0
    {
        #pragma unroll
        for (int q = 0; q < 2; ++q) {
            const short* g = A + (size_t)(bm + q * 64 + srow) * K + skc;
            GLOAD_LDS16(g, &lds[0][q * 2048 + wv * 512]);
        }
        #pragma unroll
        for (int q = 0; q < 2; ++q) {
            const short* g = Bt + (size_t)(bn + q * 64 + srow) * K + skc;
            GLOAD_LDS16(g, &lds[0][4096 + q * 2048 + wv * 512]);
        }
    }
    __syncthreads();

    int cur = 0;
    const int lr = ln & 15;
    const int lk = (ln >> 4) * 8;

    for (int kt = 0; kt < NT; ++kt) {
        if (kt + 1 < NT) {
            int k0 = (kt + 1) << 5;
            #pragma unroll
            for (int q = 0; q < 2; ++q) {
                const short* g = A + (size_t)(bm + q * 64 + srow) * K + k0 + skc;
                GLOAD_LDS16(g, &lds[cur ^ 1][q * 2048 + wv * 512]);
            }
            #pragma unroll
            for (int q = 0; q < 2; ++q) {
                const short* g = Bt + (size_t)(bn + q * 64 + srow) * K + k0 + skc;
                GLOAD_LDS16(g, &lds[cur ^ 1][4096 + q * 2048 + wv * 512]);
            }
        }

        const short* As = &lds[cur][0];
        const short* Bs = &lds[cur][4096];
        short8 a[4], b[4];
        #pragma unroll
        for (int fi = 0; fi < 4; ++fi)
            a[fi] = *(const short8*)(As + (wm * 64 + fi * 16 + lr) * 32 + lk);
        #pragma unroll
        for (int fj = 0; fj < 4; ++fj)
            b[fj] = *(const short8*)(Bs + (wn * 64 + fj * 16 + lr) * 32 + lk);
        #pragma unroll
        for (int fi = 0; fi < 4; ++fi)
            #pragma unroll
            for (int fj = 0; fj < 4; ++fj)
                acc[fi][fj] = __builtin_amdgcn_mfma_f32_16x16x32_bf16(
                    a[fi], b[fj], acc[fi][fj], 0, 0, 0);

        __syncthreads();
        cur ^= 1;
    }

    // epilogue: C row = (ln>>4)*4 + r, col = ln&15 within each 16x16 frag
    const int row0 = bm + wm * 64 + (ln >> 4) * 4;
    const int col0 = bn + wn * 64 + lr;
    #pragma unroll
    for (int fi = 0; fi < 4; ++fi) {
        #pragma unroll
        for (int r = 0; r < 4; ++r) {
            int row = row0 + fi * 16 + r;
            #pragma unroll
            for (int fj = 0; fj < 4; ++fj) {
                int col = col0 + fj * 16;
                float v = acc[fi][fj][r] + bias[col];
                if (RELU) v = fmaxf(v, 0.f);
                if (STORE_BF16)
                    ((__hip_bfloat16*)Cout)[(size_t)row * N + col] = __float2bfloat16(v);
                else
                    ((float*)Cout)[(size_t)row * N + col] = v;
            }
        }
    }
}

// ---------------------------------------------------------------------------
// Triplet MFMA: per batch b, C[j, ip] = sum_h op[b,j,h] * affine[b,ip,h]
// op: [BL][128] bf16; affine: [BL][512] bf16 (row bl=b*256+i, col p*128+h).
// B-row ip -> global row b*256 + (ip>>2), col (ip&3)*128. K=128. Out fp32.
// ---------------------------------------------------------------------------
__global__ __launch_bounds__(256) void triplet_mfma_kernel(
    const short* __restrict__ op, const short* __restrict__ affine,
    float* __restrict__ out)
{
    __shared__ __align__(16) short lds[2][8192];

    const int t  = threadIdx.x;
    const int wv = t >> 6;
    const int ln = t & 63;
    const int wm = wv >> 1;
    const int wn = wv & 1;
    const int bm = blockIdx.x * 128;    // j tile (0 or 128)
    const int bn = blockIdx.y * 128;    // ip tile
    const int b  = blockIdx.z;

    const short* Ab = op      + (size_t)b * 256 * HIDP_;
    const short* Bb = affine  + (size_t)b * 256 * NBI_;

    const int srow = t >> 2;
    const int skc  = (t & 3) * 8;

    f32x4 acc[4][4] = {};

    // stage k-tile 0
    {
        #pragma unroll
        for (int q = 0; q < 2; ++q) {
            const short* g = Ab + (size_t)(bm + q * 64 + srow) * HIDP_ + skc;
            GLOAD_LDS16(g, &lds[0][q * 2048 + wv * 512]);
        }
        #pragma unroll
        for (int q = 0; q < 2; ++q) {
            int ip = bn + q * 64 + srow;
            const short* g = Bb + (size_t)(ip >> 2) * NBI_ + (ip & 3) * HIDP_ + skc;
            GLOAD_LDS16(g, &lds[0][4096 + q * 2048 + wv * 512]);
        }
    }
    __syncthreads();

    int cur = 0;
    const int lr = ln & 15;
    const int lk = (ln >> 4) * 8;

    #pragma unroll
    for (int kt = 0; kt < 4; ++kt) {             // K=128 -> 4 steps
        if (kt + 1 < 4) {
            int k0 = (kt + 1) << 5;
            #pragma unroll
            for (int q = 0; q < 2; ++q) {
                const short* g = Ab + (size_t)(bm + q * 64 + srow) * HIDP_ + k0 + skc;
                GLOAD_LDS16(g, &lds[cur ^ 1][q * 2048 + wv * 512]);
            }
            #pragma unroll
            for (int q = 0; q < 2; ++q) {
                int ip = bn + q * 64 + srow;
                const short* g = Bb + (size_t)(ip >> 2) * NBI_ + (ip & 3) * HIDP_ + k0 + skc;
                GLOAD_LDS16(g, &lds[cur ^ 1][4096 + q * 2048 + wv * 512]);
            }
        }

        const short* As = &lds[cur][0];
        const short* Bs = &lds[cur][4096];
        short8 a[4], bf[4];
        #pragma unroll
        for (int fi = 0; fi < 4; ++fi)
            a[fi] = *(const short8*)(As + (wm * 64 + fi * 16 + lr) * 32 + lk);
        #pragma unroll
        for (int fj = 0; fj < 4; ++fj)
            bf[fj] = *(const short8*)(Bs + (wn * 64 + fj * 16 + lr) * 32 + lk);
        #pragma unroll
        for (int fi = 0; fi < 4; ++fi)
            #pragma unroll
            for (int fj = 0; fj < 4; ++fj)
                acc[fi][fj] = __builtin_amdgcn_mfma_f32_16x16x32_bf16(
                    a[fi], bf[fj], acc[fi][fj], 0, 0, 0);

        __syncthreads();
        cur ^= 1;
    }

    float* O = out + (size_t)b * 256 * 1024;
    const int row0 = bm + wm * 64 + (ln >> 4) * 4;
    const int col0 = bn + wn * 64 + lr;
    #pragma unroll
    for (int fi = 0; fi < 4; ++fi)
        #pragma unroll
        for (int r = 0; r < 4; ++r) {
            int row = row0 + fi * 16 + r;
            #pragma unroll
            for (int fj = 0; fj < 4; ++fj)
                O[(size_t)row * 1024 + col0 + fj * 16] = acc[fi][fj][r];
        }
}

// ---------------------------------------------------------------------------
// Tag heads from bf16 ap/op (stride HIDP_) -> out[0 : 163840] fp32
// ---------------------------------------------------------------------------
__global__ __launch_bounds__(256) void tag_kernel(
    const __hip_bfloat16* __restrict__ ap, const __hip_bfloat16* __restrict__ op,
    const float* __restrict__ Wap, const float* __restrict__ bap,
    const float* __restrict__ Wop, const float* __restrict__ bop,
    float* __restrict__ out)
{
    int idx = blockIdx.x * 256 + threadIdx.x;
    if (idx >= 2 * BL_ * TAGS_) return;
    int half = idx / (BL_ * TAGS_);
    int r    = idx % (BL_ * TAGS_);
    int row  = r / TAGS_;
    int tg   = r % TAGS_;
    const __hip_bfloat16* x = (half ? op : ap) + (size_t)row * HIDP_;
    const float* W = half ? Wop : Wap;
    float s = (half ? bop : bap)[tg];
    #pragma unroll 4
    for (int k = 0; k < HID_; ++k) s += __bfloat162float(x[k]) * W[k * TAGS_ + tg];
    out[idx] = s;
}

// ---------------------------------------------------------------------------
extern "C" void kernel_launch(void* const* d_in, const int* in_sizes, int n_in,
                              void* d_out, int out_size, void* d_ws, size_t ws_size,
                              hipStream_t stream)
{
    const float* bert     = (const float*)d_in[0];
    const int*   pos      = (const int*)  d_in[1];
    const float* W_reduc  = (const float*)d_in[2];
    const float* b_reduc  = (const float*)d_in[3];
    const float* W_ap     = (const float*)d_in[4];
    const float* b_ap     = (const float*)d_in[5];
    const float* W_op     = (const float*)d_in[6];
    const float* b_op     = (const float*)d_in[7];
    const float* W_ap_tag = (const float*)d_in[8];
    const float* b_ap_tag = (const float*)d_in[9];
    const float* W_op_tag = (const float*)d_in[10];
    const float* b_op_tag = (const float*)d_in[11];
    const float* W_bi     = (const float*)d_in[12];

    float* out = (float*)d_out;

    // Workspace layout (bytes)
    char* ws = (char*)d_ws;
    __hip_bfloat16* pooled = (__hip_bfloat16*)ws;                  ws += (size_t)BL_ * D_ * 2;     // 25.2 MB
    __hip_bfloat16* h      = (__hip_bfloat16*)ws;                  ws += (size_t)BL_ * REDP_ * 2;  // 16.8 MB
    __hip_bfloat16* ap     = (__hip_bfloat16*)ws;                  ws += (size_t)BL_ * HIDP_ * 2;  // 4.2 MB
    __hip_bfloat16* opv    = (__hip_bfloat16*)ws;                  ws += (size_t)BL_ * HIDP_ * 2;
    __hip_bfloat16* affine = (__hip_bfloat16*)ws;                  ws += (size_t)BL_ * NBI_ * 2;   // 16.8 MB
    __hip_bfloat16* WtR    = (__hip_bfloat16*)ws;                  ws += (size_t)REDP_ * D_ * 2;
    __hip_bfloat16* WtA    = (__hip_bfloat16*)ws;                  ws += (size_t)HIDP_ * REDP_ * 2;
    __hip_bfloat16* WtO    = (__hip_bfloat16*)ws;                  ws += (size_t)HIDP_ * REDP_ * 2;
    __hip_bfloat16* WtBi   = (__hip_bfloat16*)ws;                  ws += (size_t)NBI_ * HIDP_ * 2;
    float* bR  = (float*)ws;                                       ws += REDP_ * 4;
    float* bA  = (float*)ws;                                       ws += HIDP_ * 4;
    float* bO  = (float*)ws;                                       ws += HIDP_ * 4;
    float* bBi = (float*)ws;                                       ws += NBI_ * 4;

    // --- weight prep (bf16, transposed [N][K], zero-padded) ---
    prep_wt_kernel<<<(REDP_ * D_ + 255) / 256, 256, 0, stream>>>(
        W_reduc, RED_, D_, RED_, WtR, D_, REDP_);
    prep_wt_kernel<<<(HIDP_ * REDP_ + 255) / 256, 256, 0, stream>>>(
        W_ap, HID_, RED_, HID_, WtA, REDP_, HIDP_);
    prep_wt_kernel<<<(HIDP_ * REDP_ + 255) / 256, 256, 0, stream>>>(
        W_op, HID_, RED_, HID_, WtO, REDP_, HIDP_);
    prep_wtbi_kernel<<<(NBI_ * HIDP_ + 255) / 256, 256, 0, stream>>>(W_bi, WtBi, bBi);
    prep_bias_kernel<<<2, 256, 0, stream>>>(b_reduc, RED_, bR, REDP_);
    prep_bias_kernel<<<1, 256, 0, stream>>>(b_ap, HID_, bA, HIDP_);
    prep_bias_kernel<<<1, 256, 0, stream>>>(b_op, HID_, bO, HIDP_);

    // --- 1) segment mean (fp32 -> bf16) ---
    seg_mean_kernel<<<BL_, 256, 0, stream>>>(bert, pos, pooled);

    // --- 2) h = relu(pooled @ W_reduc + b), [16384,768] x [512,768]^T ---
    gemm_mfma_kernel<true, true><<<dim3(BL_ / 128, REDP_ / 128), 256, 0, stream>>>(
        (const short*)pooled, (const short*)WtR, bR, h, BL_, REDP_, D_);

    // --- 3) ap / op = relu(h @ W + b), [16384,512] x [128,512]^T ---
    gemm_mfma_kernel<true, true><<<dim3(BL_ / 128, HIDP_ / 128), 256, 0, stream>>>(
        (const short*)h, (const short*)WtA, bA, ap, BL_, HIDP_, REDP_);
    gemm_mfma_kernel<true, true><<<dim3(BL_ / 128, HIDP_ / 128), 256, 0, stream>>>(
        (const short*)h, (const short*)WtO, bO, opv, BL_, HIDP_, REDP_);

    // --- 4) affine = ap @ W_bi[:100] + W_bi[100], [16384,128] x [512,128]^T ---
    gemm_mfma_kernel<false, true><<<dim3(BL_ / 128, NBI_ / 128), 256, 0, stream>>>(
        (const short*)ap, (const short*)WtBi, bBi, affine, BL_, NBI_, HIDP_);

    // --- 5) tag heads -> out[0 : 163840] ---
    tag_kernel<<<(2 * BL_ * TAGS_ + 255) / 256, 256, 0, stream>>>(
        ap, opv, W_ap_tag, b_ap_tag, W_op_tag, b_op_tag, out);

    // --- 6) triplet -> out[163840 : ] ---
    triplet_mfma_kernel<<<dim3(2, 8, B_), 256, 0, stream>>>(
        (const short*)opv, (const short*)affine, out + 2 * BL_ * TAGS_);
}

// Round 4
// 95.040 us; speedup vs baseline: 6.4323x; 1.2809x over previous
//
#include <hip/hip_runtime.h>
#include <hip/hip_bf16.h>

// Problem constants
#define B_    64
#define S_    512
#define L_    256
#define D_    768      // K of GEMM1 (multiple of 32)
#define RED_  400
#define REDP_ 512      // padded N of GEMM1 / K of GEMM2-3
#define HID_  100
#define HIDP_ 128      // padded N of GEMM2-3 / K of affine+triplet
#define TAGS_ 5
#define POL_  4
#define NBI_  512      // padded N of affine GEMM (4 * 128)
#define NAO_  256      // fused ap|op GEMM N
#define BL_   (B_ * L_)  // 16384

typedef __attribute__((ext_vector_type(8))) short short8;
typedef __attribute__((ext_vector_type(4))) float f32x4;
typedef __attribute__((ext_vector_type(4))) unsigned short u16x4;

#define GLOAD_LDS16(gp, lp) __builtin_amdgcn_global_load_lds( \
    (const __attribute__((address_space(1))) void*)(gp),      \
    (__attribute__((address_space(3))) void*)(lp), 16, 0, 0)

__device__ inline float bf2f(unsigned short u) {
    union { unsigned int i; float f; } c; c.i = ((unsigned)u) << 16; return c.f;
}
__device__ inline unsigned short f2bf(float f) {
    __hip_bfloat16 h = __float2bfloat16(f);
    unsigned short u;
    __builtin_memcpy(&u, &h, 2);
    return u;
}

// ---------------------------------------------------------------------------
// 0) Fused weight/bias prep (one launch). Regions:
//    [0, 393216)          WtR  [512][768]: WtR[n*768+k] = W_reduc[k*400+n] (n<400)
//    [.., +131072)        WtAO [256][512]: n<128 -> W_ap col n (n<100); n>=128 -> W_op
//    [.., +65536)         WtBi [512][128]: n=p*128+h -> W_bi[k*400 + p*100 + h]
//                         (+ bBi[n] from W_bi row 100 when k==0)
//    [.., +512)           bR   padded b_reduc
//    [.., +256)           bAO  [b_ap pad 128 | b_op pad 128]
// ---------------------------------------------------------------------------
#define SZ0 393216
#define SZ1 131072
#define SZ2 65536
#define SZ3 512
#define SZ4 256
#define PREP_TOT (SZ0 + SZ1 + SZ2 + SZ3 + SZ4)

__global__ __launch_bounds__(256) void prep_kernel(
    const float* __restrict__ W_reduc, const float* __restrict__ b_reduc,
    const float* __restrict__ W_ap, const float* __restrict__ b_ap,
    const float* __restrict__ W_op, const float* __restrict__ b_op,
    const float* __restrict__ W_bi,
    unsigned short* __restrict__ WtR, unsigned short* __restrict__ WtAO,
    unsigned short* __restrict__ WtBi,
    float* __restrict__ bR, float* __restrict__ bAO, float* __restrict__ bBi)
{
    int idx = blockIdx.x * 256 + threadIdx.x;
    if (idx < SZ0) {
        int n = idx / D_, k = idx - n * D_;
        float v = (n < RED_) ? W_reduc[(size_t)k * RED_ + n] : 0.f;
        WtR[idx] = f2bf(v);
    } else if (idx < SZ0 + SZ1) {
        int i = idx - SZ0;
        int n = i >> 9, k = i & 511;
        float v = 0.f;
        if (k < RED_) {
            if (n < HID_)                      v = W_ap[(size_t)k * HID_ + n];
            else if (n >= 128 && n < 128+HID_) v = W_op[(size_t)k * HID_ + (n-128)];
        }
        WtAO[i] = f2bf(v);
    } else if (idx < SZ0 + SZ1 + SZ2) {
        int i = idx - SZ0 - SZ1;
        int n = i >> 7, k = i & 127;
        int p = n >> 7, h = n & 127;
        float v = (h < HID_ && k < HID_) ? W_bi[(size_t)k * RED_ + p * HID_ + h] : 0.f;
        WtBi[i] = f2bf(v);
        if (k == 0) bBi[n] = (h < HID_) ? W_bi[(size_t)HID_ * RED_ + p * HID_ + h] : 0.f;
    } else if (idx < SZ0 + SZ1 + SZ2 + SZ3) {
        int n = idx - SZ0 - SZ1 - SZ2;
        bR[n] = (n < RED_) ? b_reduc[n] : 0.f;
    } else if (idx < PREP_TOT) {
        int n = idx - SZ0 - SZ1 - SZ2 - SZ3;
        bAO[n] = (n < 128) ? ((n < HID_) ? b_ap[n] : 0.f)
                           : (((n-128) < HID_) ? b_op[n-128] : 0.f);
    }
}

// ---------------------------------------------------------------------------
// 1) Segment mean -> bf16 pooled [BL, 768]. 4 rows/block, float4 loads.
// ---------------------------------------------------------------------------
__global__ __launch_bounds__(256) void seg_mean_kernel(
    const float* __restrict__ bert, const int* __restrict__ pos,
    unsigned short* __restrict__ pooled)
{
    int r  = threadIdx.x >> 6;          // 0..3
    int l  = threadIdx.x & 63;
    int bl = blockIdx.x * 4 + r;        // 0..16383
    int b  = bl >> 8;
    int s  = pos[bl * 2 + 0];
    int e  = pos[bl * 2 + 1];
    int len = e - s + 1;                // 1 or 2
    const float* v0 = bert + ((size_t)b * S_ + s) * D_;
    float inv = (len == 2) ? 0.5f : 1.0f;
    unsigned short* outp = pooled + (size_t)bl * D_;
    #pragma unroll
    for (int c = 0; c < 3; ++c) {
        int d = l * 4 + c * 256;
        f32x4 x = *(const f32x4*)(v0 + d);
        if (len == 2) {
            f32x4 y = *(const f32x4*)(v0 + D_ + d);
            x += y;
        }
        u16x4 o;
        #pragma unroll
        for (int j = 0; j < 4; ++j) o[j] = f2bf(x[j] * inv);
        *(u16x4*)(outp + d) = o;
    }
}

// ---------------------------------------------------------------------------
// MFMA GEMM: C = act(A[M,K] @ Bt[N,K]^T + bias[N]); bf16 in, bf16 out.
// 128x128 tile, BK=32, 4 waves (2x2), 64x64/wave, double-buffered LDS,
// global_load_lds width 16. SPLIT: N=256, y-tile 0 -> C1[.,128], 1 -> C2.
// ---------------------------------------------------------------------------
template <bool RELU, bool SPLIT>
__global__ __launch_bounds__(256) void gemm_mfma_kernel(
    const short* __restrict__ A, const short* __restrict__ Bt,
    const float* __restrict__ bias, void* __restrict__ Cout,
    void* __restrict__ Cout2, int M, int N, int K)
{
    __shared__ __align__(16) short lds[2][8192];   // [buf][A 4096 | B 4096]

    const int t  = threadIdx.x;
    const int wv = t >> 6;
    const int ln = t & 63;
    const int wm = wv >> 1;
    const int wn = wv & 1;
    const int bm = blockIdx.x * 128;
    const int bn = blockIdx.y * 128;

    const int srow = t >> 2;
    const int skc  = (t & 3) * 8;

    f32x4 acc[4][4] = {};

    const int NT = K >> 5;

    {
        #pragma unroll
        for (int q = 0; q < 2; ++q) {
            const short* g = A + (size_t)(bm + q * 64 + srow) * K + skc;
            GLOAD_LDS16(g, &lds[0][q * 2048 + wv * 512]);
        }
        #pragma unroll
        for (int q = 0; q < 2; ++q) {
            const short* g = Bt + (size_t)(bn + q * 64 + srow) * K + skc;
            GLOAD_LDS16(g, &lds[0][4096 + q * 2048 + wv * 512]);
        }
    }
    __syncthreads();

    int cur = 0;
    const int lr = ln & 15;
    const int lk = (ln >> 4) * 8;

    for (int kt = 0; kt < NT; ++kt) {
        if (kt + 1 < NT) {
            int k0 = (kt + 1) << 5;
            #pragma unroll
            for (int q = 0; q < 2; ++q) {
                const short* g = A + (size_t)(bm + q * 64 + srow) * K + k0 + skc;
                GLOAD_LDS16(g, &lds[cur ^ 1][q * 2048 + wv * 512]);
            }
            #pragma unroll
            for (int q = 0; q < 2; ++q) {
                const short* g = Bt + (size_t)(bn + q * 64 + srow) * K + k0 + skc;
                GLOAD_LDS16(g, &lds[cur ^ 1][4096 + q * 2048 + wv * 512]);
            }
        }

        const short* As = &lds[cur][0];
        const short* Bs = &lds[cur][4096];
        short8 a[4], b[4];
        #pragma unroll
        for (int fi = 0; fi < 4; ++fi)
            a[fi] = *(const short8*)(As + (wm * 64 + fi * 16 + lr) * 32 + lk);
        #pragma unroll
        for (int fj = 0; fj < 4; ++fj)
            b[fj] = *(const short8*)(Bs + (wn * 64 + fj * 16 + lr) * 32 + lk);
        #pragma unroll
        for (int fi = 0; fi < 4; ++fi)
            #pragma unroll
            for (int fj = 0; fj < 4; ++fj)
                acc[fi][fj] = __builtin_amdgcn_mfma_f32_16x16x32_bf16(
                    a[fi], b[fj], acc[fi][fj], 0, 0, 0);

        __syncthreads();
        cur ^= 1;
    }

    const int row0    = bm + wm * 64 + (ln >> 4) * 4;
    const int colloc0 = wn * 64 + lr;
    if (SPLIT) {
        unsigned short* Co = (unsigned short*)(bn ? Cout2 : Cout);
        #pragma unroll
        for (int fi = 0; fi < 4; ++fi)
            #pragma unroll
            for (int r = 0; r < 4; ++r) {
                int row = row0 + fi * 16 + r;
                #pragma unroll
                for (int fj = 0; fj < 4; ++fj) {
                    int cl = colloc0 + fj * 16;
                    float v = acc[fi][fj][r] + bias[bn + cl];
                    if (RELU) v = fmaxf(v, 0.f);
                    Co[(size_t)row * 128 + cl] = f2bf(v);
                }
            }
    } else {
        unsigned short* Co = (unsigned short*)Cout;
        #pragma unroll
        for (int fi = 0; fi < 4; ++fi)
            #pragma unroll
            for (int r = 0; r < 4; ++r) {
                int row = row0 + fi * 16 + r;
                #pragma unroll
                for (int fj = 0; fj < 4; ++fj) {
                    int col = bn + colloc0 + fj * 16;
                    float v = acc[fi][fj][r] + bias[col];
                    if (RELU) v = fmaxf(v, 0.f);
                    Co[(size_t)row * N + col] = f2bf(v);
                }
            }
    }
}

// ---------------------------------------------------------------------------
// Triplet MFMA: per batch b, C[j, ip] = sum_h op[b,j,h] * affine[b,ip,h]
// op [BL][128] bf16; affine [BL][512] bf16 (row bl=b*256+i, col p*128+h).
// ---------------------------------------------------------------------------
__global__ __launch_bounds__(256) void triplet_mfma_kernel(
    const short* __restrict__ op, const short* __restrict__ affine,
    float* __restrict__ out)
{
    __shared__ __align__(16) short lds[2][8192];

    const int t  = threadIdx.x;
    const int wv = t >> 6;
    const int ln = t & 63;
    const int wm = wv >> 1;
    const int wn = wv & 1;
    const int bm = blockIdx.x * 128;
    const int bn = blockIdx.y * 128;
    const int b  = blockIdx.z;

    const short* Ab = op     + (size_t)b * 256 * HIDP_;
    const short* Bb = affine + (size_t)b * 256 * NBI_;

    const int srow = t >> 2;
    const int skc  = (t & 3) * 8;

    f32x4 acc[4][4] = {};

    {
        #pragma unroll
        for (int q = 0; q < 2; ++q) {
            const short* g = Ab + (size_t)(bm + q * 64 + srow) * HIDP_ + skc;
            GLOAD_LDS16(g, &lds[0][q * 2048 + wv * 512]);
        }
        #pragma unroll
        for (int q = 0; q < 2; ++q) {
            int ip = bn + q * 64 + srow;
            const short* g = Bb + (size_t)(ip >> 2) * NBI_ + (ip & 3) * HIDP_ + skc;
            GLOAD_LDS16(g, &lds[0][4096 + q * 2048 + wv * 512]);
        }
    }
    __syncthreads();

    int cur = 0;
    const int lr = ln & 15;
    const int lk = (ln >> 4) * 8;

    #pragma unroll
    for (int kt = 0; kt < 4; ++kt) {
        if (kt + 1 < 4) {
            int k0 = (kt + 1) << 5;
            #pragma unroll
            for (int q = 0; q < 2; ++q) {
                const short* g = Ab + (size_t)(bm + q * 64 + srow) * HIDP_ + k0 + skc;
                GLOAD_LDS16(g, &lds[cur ^ 1][q * 2048 + wv * 512]);
            }
            #pragma unroll
            for (int q = 0; q < 2; ++q) {
                int ip = bn + q * 64 + srow;
                const short* g = Bb + (size_t)(ip >> 2) * NBI_ + (ip & 3) * HIDP_ + k0 + skc;
                GLOAD_LDS16(g, &lds[cur ^ 1][4096 + q * 2048 + wv * 512]);
            }
        }

        const short* As = &lds[cur][0];
        const short* Bs = &lds[cur][4096];
        short8 a[4], bf[4];
        #pragma unroll
        for (int fi = 0; fi < 4; ++fi)
            a[fi] = *(const short8*)(As + (wm * 64 + fi * 16 + lr) * 32 + lk);
        #pragma unroll
        for (int fj = 0; fj < 4; ++fj)
            bf[fj] = *(const short8*)(Bs + (wn * 64 + fj * 16 + lr) * 32 + lk);
        #pragma unroll
        for (int fi = 0; fi < 4; ++fi)
            #pragma unroll
            for (int fj = 0; fj < 4; ++fj)
                acc[fi][fj] = __builtin_amdgcn_mfma_f32_16x16x32_bf16(
                    a[fi], bf[fj], acc[fi][fj], 0, 0, 0);

        __syncthreads();
        cur ^= 1;
    }

    float* O = out + (size_t)b * 256 * 1024;
    const int row0 = bm + wm * 64 + (ln >> 4) * 4;
    const int col0 = bn + wn * 64 + lr;
    #pragma unroll
    for (int fi = 0; fi < 4; ++fi)
        #pragma unroll
        for (int r = 0; r < 4; ++r) {
            int row = row0 + fi * 16 + r;
            #pragma unroll
            for (int fj = 0; fj < 4; ++fj)
                O[(size_t)row * 1024 + col0 + fj * 16] = acc[fi][fj][r];
        }
}

// ---------------------------------------------------------------------------
// Tag heads: one row per thread, both halves. W in LDS. out fp32.
// ---------------------------------------------------------------------------
__global__ __launch_bounds__(256) void tag_kernel(
    const short* __restrict__ ap, const short* __restrict__ op,
    const float* __restrict__ Wap, const float* __restrict__ bap,
    const float* __restrict__ Wop, const float* __restrict__ bop,
    float* __restrict__ out)
{
    __shared__ float Wl[2][HID_][TAGS_];
    __shared__ float bl[2][TAGS_];
    int t = threadIdx.x;
    for (int i = t; i < HID_ * TAGS_; i += 256) {
        Wl[0][i / TAGS_][i % TAGS_] = Wap[i];
        Wl[1][i / TAGS_][i % TAGS_] = Wop[i];
    }
    if (t < TAGS_) { bl[0][t] = bap[t]; bl[1][t] = bop[t]; }
    __syncthreads();

    int row = blockIdx.x * 256 + t;
    #pragma unroll
    for (int half = 0; half < 2; ++half) {
        const short* x = (half ? op : ap) + (size_t)row * HIDP_;
        float s[TAGS_];
        #pragma unroll
        for (int g = 0; g < TAGS_; ++g) s[g] = bl[half][g];
        #pragma unroll
        for (int c = 0; c < 12; ++c) {
            short8 v = *(const short8*)(x + c * 8);
            #pragma unroll
            for (int j = 0; j < 8; ++j) {
                float xv = bf2f((unsigned short)v[j]);
                int k = c * 8 + j;
                #pragma unroll
                for (int g = 0; g < TAGS_; ++g) s[g] += xv * Wl[half][k][g];
            }
        }
        #pragma unroll
        for (int k = 96; k < HID_; ++k) {
            float xv = bf2f(*(const unsigned short*)(x + k));
            #pragma unroll
            for (int g = 0; g < TAGS_; ++g) s[g] += xv * Wl[half][k][g];
        }
        float* o = out + (size_t)half * (BL_ * TAGS_) + (size_t)row * TAGS_;
        #pragma unroll
        for (int g = 0; g < TAGS_; ++g) o[g] = s[g];
    }
}

// ---------------------------------------------------------------------------
extern "C" void kernel_launch(void* const* d_in, const int* in_sizes, int n_in,
                              void* d_out, int out_size, void* d_ws, size_t ws_size,
                              hipStream_t stream)
{
    const float* bert     = (const float*)d_in[0];
    const int*   pos      = (const int*)  d_in[1];
    const float* W_reduc  = (const float*)d_in[2];
    const float* b_reduc  = (const float*)d_in[3];
    const float* W_ap     = (const float*)d_in[4];
    const float* b_ap     = (const float*)d_in[5];
    const float* W_op     = (const float*)d_in[6];
    const float* b_op     = (const float*)d_in[7];
    const float* W_ap_tag = (const float*)d_in[8];
    const float* b_ap_tag = (const float*)d_in[9];
    const float* W_op_tag = (const float*)d_in[10];
    const float* b_op_tag = (const float*)d_in[11];
    const float* W_bi     = (const float*)d_in[12];

    float* out = (float*)d_out;

    // Workspace layout (bytes; all 16B-aligned)
    char* ws = (char*)d_ws;
    unsigned short* pooled = (unsigned short*)ws; ws += (size_t)BL_ * D_ * 2;
    unsigned short* h      = (unsigned short*)ws; ws += (size_t)BL_ * REDP_ * 2;
    unsigned short* ap     = (unsigned short*)ws; ws += (size_t)BL_ * HIDP_ * 2;
    unsigned short* opv    = (unsigned short*)ws; ws += (size_t)BL_ * HIDP_ * 2;
    unsigned short* affine = (unsigned short*)ws; ws += (size_t)BL_ * NBI_ * 2;
    unsigned short* WtR    = (unsigned short*)ws; ws += (size_t)REDP_ * D_ * 2;
    unsigned short* WtAO   = (unsigned short*)ws; ws += (size_t)NAO_ * REDP_ * 2;
    unsigned short* WtBi   = (unsigned short*)ws; ws += (size_t)NBI_ * HIDP_ * 2;
    float* bR  = (float*)ws;  ws += REDP_ * 4;
    float* bAO = (float*)ws;  ws += NAO_ * 4;
    float* bBi = (float*)ws;  ws += NBI_ * 4;

    // 0) fused weight/bias prep
    prep_kernel<<<(PREP_TOT + 255) / 256, 256, 0, stream>>>(
        W_reduc, b_reduc, W_ap, b_ap, W_op, b_op, W_bi,
        WtR, WtAO, WtBi, bR, bAO, bBi);

    // 1) segment mean (fp32 -> bf16)
    seg_mean_kernel<<<BL_ / 4, 256, 0, stream>>>(bert, pos, pooled);

    // 2) h = relu(pooled @ W_reduc + b)  [16384,768] x [512,768]^T
    gemm_mfma_kernel<true, false><<<dim3(BL_ / 128, REDP_ / 128), 256, 0, stream>>>(
        (const short*)pooled, (const short*)WtR, bR, h, nullptr, BL_, REDP_, D_);

    // 3) ap|op = relu(h @ [W_ap|W_op] + b)  [16384,512] x [256,512]^T, split out
    gemm_mfma_kernel<true, true><<<dim3(BL_ / 128, NAO_ / 128), 256, 0, stream>>>(
        (const short*)h, (const short*)WtAO, bAO, ap, opv, BL_, NAO_, REDP_);

    // 4) affine = ap @ W_bi[:100] + W_bi[100]  [16384,128] x [512,128]^T
    gemm_mfma_kernel<false, false><<<dim3(BL_ / 128, NBI_ / 128), 256, 0, stream>>>(
        (const short*)ap, (const short*)WtBi, bBi, affine, nullptr, BL_, NBI_, HIDP_);

    // 5) tag heads -> out[0 : 163840]
    tag_kernel<<<BL_ / 256, 256, 0, stream>>>(
        (const short*)ap, (const short*)opv,
        W_ap_tag, b_ap_tag, W_op_tag, b_op_tag, out);

    // 6) triplet -> out[163840 : ]
    triplet_mfma_kernel<<<dim3(2, 8, B_), 256, 0, stream>>>(
        (const short*)opv, (const short*)affine, out + 2 * BL_ * TAGS_);
}

// Round 6
// 84.499 us; speedup vs baseline: 7.2348x; 1.1247x over previous
//
#include <hip/hip_runtime.h>
#include <hip/hip_bf16.h>

// Problem constants
#define B_    64
#define S_    512
#define L_    256
#define D_    768      // K of GEMM1
#define RED_  400
#define REDP_ 512      // padded N of GEMM1 / K of GEMM23
#define HID_  100
#define HIDP_ 128      // padded N of GEMM23 / K of affine+triplet
#define TAGS_ 5
#define POL_  4
#define NBI_  512      // padded N of affine GEMM (4 * 128)
#define NAO_  256      // fused ap|op GEMM N
#define BL_   (B_ * L_)  // 16384

typedef __attribute__((ext_vector_type(8))) short short8;
typedef __attribute__((ext_vector_type(4))) float f32x4;
typedef __attribute__((ext_vector_type(4))) unsigned short u16x4;

#define GLOAD_LDS16(gp, lp) __builtin_amdgcn_global_load_lds( \
    (const __attribute__((address_space(1))) void*)(gp),      \
    (__attribute__((address_space(3))) void*)(lp), 16, 0, 0)

__device__ inline float bf2f(unsigned short u) {
    union { unsigned int i; float f; } c; c.i = ((unsigned)u) << 16; return c.f;
}
__device__ inline unsigned short f2bf(float f) {
    __hip_bfloat16 h = __float2bfloat16(f);
    unsigned short u;
    __builtin_memcpy(&u, &h, 2);
    return u;
}

// ---------------------------------------------------------------------------
// 0+1) FRONT: blocks [0,4096) = segment mean (4 rows/block, float4 loads);
//      blocks [4096, ...) = weight/bias prep (grid-elementwise).
// ---------------------------------------------------------------------------
#define SZ0 393216
#define SZ1 131072
#define SZ2 65536
#define SZ3 512
#define SZ4 256
#define PREP_TOT (SZ0 + SZ1 + SZ2 + SZ3 + SZ4)
#define SEG_BLOCKS (BL_ / 4)
#define PREP_BLOCKS ((PREP_TOT + 255) / 256)

__global__ __launch_bounds__(256) void front_kernel(
    const float* __restrict__ bert, const int* __restrict__ pos,
    unsigned short* __restrict__ pooled,
    const float* __restrict__ W_reduc, const float* __restrict__ b_reduc,
    const float* __restrict__ W_ap, const float* __restrict__ b_ap,
    const float* __restrict__ W_op, const float* __restrict__ b_op,
    const float* __restrict__ W_bi,
    unsigned short* __restrict__ WtR, unsigned short* __restrict__ WtAO,
    unsigned short* __restrict__ WtBi,
    float* __restrict__ bR, float* __restrict__ bAO, float* __restrict__ bBi)
{
    if (blockIdx.x < SEG_BLOCKS) {
        int r  = threadIdx.x >> 6;
        int l  = threadIdx.x & 63;
        int bl = blockIdx.x * 4 + r;
        int b  = bl >> 8;
        int s  = pos[bl * 2 + 0];
        int e  = pos[bl * 2 + 1];
        int len = e - s + 1;                // 1 or 2
        const float* v0 = bert + ((size_t)b * S_ + s) * D_;
        float inv = (len == 2) ? 0.5f : 1.0f;
        unsigned short* outp = pooled + (size_t)bl * D_;
        #pragma unroll
        for (int c = 0; c < 3; ++c) {
            int d = l * 4 + c * 256;
            f32x4 x = *(const f32x4*)(v0 + d);
            if (len == 2) {
                f32x4 y = *(const f32x4*)(v0 + D_ + d);
                x += y;
            }
            u16x4 o;
            #pragma unroll
            for (int j = 0; j < 4; ++j) o[j] = f2bf(x[j] * inv);
            *(u16x4*)(outp + d) = o;
        }
        return;
    }

    int idx = (blockIdx.x - SEG_BLOCKS) * 256 + threadIdx.x;
    if (idx < SZ0) {
        int n = idx / D_, k = idx - n * D_;
        float v = (n < RED_) ? W_reduc[(size_t)k * RED_ + n] : 0.f;
        WtR[idx] = f2bf(v);
    } else if (idx < SZ0 + SZ1) {
        int i = idx - SZ0;
        int n = i >> 9, k = i & 511;
        float v = 0.f;
        if (k < RED_) {
            if (n < HID_)                      v = W_ap[(size_t)k * HID_ + n];
            else if (n >= 128 && n < 128+HID_) v = W_op[(size_t)k * HID_ + (n-128)];
        }
        WtAO[i] = f2bf(v);
    } else if (idx < SZ0 + SZ1 + SZ2) {
        int i = idx - SZ0 - SZ1;
        int n = i >> 7, k = i & 127;
        int p = n >> 7, h = n & 127;
        float v = (h < HID_ && k < HID_) ? W_bi[(size_t)k * RED_ + p * HID_ + h] : 0.f;
        WtBi[i] = f2bf(v);
        if (k == 0) bBi[n] = (h < HID_) ? W_bi[(size_t)HID_ * RED_ + p * HID_ + h] : 0.f;
    } else if (idx < SZ0 + SZ1 + SZ2 + SZ3) {
        int n = idx - SZ0 - SZ1 - SZ2;
        bR[n] = (n < RED_) ? b_reduc[n] : 0.f;
    } else if (idx < PREP_TOT) {
        int n = idx - SZ0 - SZ1 - SZ2 - SZ3;
        bAO[n] = (n < 128) ? ((n < HID_) ? b_ap[n] : 0.f)
                           : (((n-128) < HID_) ? b_op[n-128] : 0.f);
    }
}

// ---------------------------------------------------------------------------
// 2) GEMM1: h = relu(pooled[16384,768] @ WtR[512,768]^T + bR) -> bf16
// 128x128 tile, BK=32, 4 waves (2x2), double-buffered, global_load_lds x16.
// ---------------------------------------------------------------------------
__global__ __launch_bounds__(256) void gemm1_kernel(
    const short* __restrict__ A, const short* __restrict__ Bt,
    const float* __restrict__ bias, unsigned short* __restrict__ Co,
    int M, int N, int K)
{
    __shared__ __align__(16) short lds[2][8192];   // [buf][A 4096 | B 4096]

    const int t  = threadIdx.x;
    const int wv = t >> 6;
    const int ln = t & 63;
    const int wm = wv >> 1;
    const int wn = wv & 1;
    const int bm = blockIdx.x * 128;
    const int bn = blockIdx.y * 128;

    const int srow = t >> 2;
    const int skc  = (t & 3) * 8;

    f32x4 acc[4][4] = {};
    const int NT = K >> 5;

    {
        #pragma unroll
        for (int q = 0; q < 2; ++q) {
            const short* g = A + (size_t)(bm + q * 64 + srow) * K + skc;
            GLOAD_LDS16(g, &lds[0][q * 2048 + wv * 512]);
        }
        #pragma unroll
        for (int q = 0; q < 2; ++q) {
            const short* g = Bt + (size_t)(bn + q * 64 + srow) * K + skc;
            GLOAD_LDS16(g, &lds[0][4096 + q * 2048 + wv * 512]);
        }
    }
    __syncthreads();

    int cur = 0;
    const int lr = ln & 15;
    const int lk = (ln >> 4) * 8;

    for (int kt = 0; kt < NT; ++kt) {
        if (kt + 1 < NT) {
            int k0 = (kt + 1) << 5;
            #pragma unroll
            for (int q = 0; q < 2; ++q) {
                const short* g = A + (size_t)(bm + q * 64 + srow) * K + k0 + skc;
                GLOAD_LDS16(g, &lds[cur ^ 1][q * 2048 + wv * 512]);
            }
            #pragma unroll
            for (int q = 0; q < 2; ++q) {
                const short* g = Bt + (size_t)(bn + q * 64 + srow) * K + k0 + skc;
                GLOAD_LDS16(g, &lds[cur ^ 1][4096 + q * 2048 + wv * 512]);
            }
        }

        const short* As = &lds[cur][0];
        const short* Bs = &lds[cur][4096];
        short8 a[4], b[4];
        #pragma unroll
        for (int fi = 0; fi < 4; ++fi)
            a[fi] = *(const short8*)(As + (wm * 64 + fi * 16 + lr) * 32 + lk);
        #pragma unroll
        for (int fj = 0; fj < 4; ++fj)
            b[fj] = *(const short8*)(Bs + (wn * 64 + fj * 16 + lr) * 32 + lk);
        #pragma unroll
        for (int fi = 0; fi < 4; ++fi)
            #pragma unroll
            for (int fj = 0; fj < 4; ++fj)
                acc[fi][fj] = __builtin_amdgcn_mfma_f32_16x16x32_bf16(
                    a[fi], b[fj], acc[fi][fj], 0, 0, 0);

        __syncthreads();
        cur ^= 1;
    }

    const int row0 = bm + wm * 64 + (ln >> 4) * 4;
    const int col0 = bn + wn * 64 + lr;
    #pragma unroll
    for (int fi = 0; fi < 4; ++fi)
        #pragma unroll
        for (int r = 0; r < 4; ++r) {
            int row = row0 + fi * 16 + r;
            #pragma unroll
            for (int fj = 0; fj < 4; ++fj) {
                int col = col0 + fj * 16;
                float v = fmaxf(acc[fi][fj][r] + bias[col], 0.f);
                Co[(size_t)row * N + col] = f2bf(v);
            }
        }
}

// ---------------------------------------------------------------------------
// 3) GEMM23 + tag heads: [ap|op] = relu(h @ WtAO^T + bAO), split outputs;
//    epilogue keeps the 128x128 tile in LDS (fp32) and computes the 5-tag
//    head for its rows. grid (128, 2): by=0 -> ap, by=1 -> op. K=512.
// ---------------------------------------------------------------------------
__global__ __launch_bounds__(256) void gemm23_tag_kernel(
    const short* __restrict__ A, const short* __restrict__ Bt,
    const float* __restrict__ bias,
    unsigned short* __restrict__ apOut, unsigned short* __restrict__ opOut,
    const float* __restrict__ Wap_tag, const float* __restrict__ bap_tag,
    const float* __restrict__ Wop_tag, const float* __restrict__ bop_tag,
    float* __restrict__ out_tag)
{
    __shared__ __align__(16) short lds[2][8192];
    __shared__ float tagf[128 * 101];     // fp32 tile for tag reduction
    __shared__ float Wtag[HID_ * TAGS_];
    __shared__ float Btag[TAGS_];

    const int t  = threadIdx.x;
    const int wv = t >> 6;
    const int ln = t & 63;
    const int wm = wv >> 1;
    const int wn = wv & 1;
    const int bm = blockIdx.x * 128;
    const int bn = blockIdx.y * 128;   // 0 -> ap, 128 -> op
    const int half = blockIdx.y;

    const float* Wt = half ? Wop_tag : Wap_tag;
    const float* bt = half ? bop_tag : bap_tag;
    for (int i = t; i < HID_ * TAGS_; i += 256) Wtag[i] = Wt[i];   // 500 > 256!
    if (t < TAGS_) Btag[t] = bt[t];

    const int srow = t >> 2;
    const int skc  = (t & 3) * 8;
    const int K = REDP_;

    f32x4 acc[4][4] = {};

    {
        #pragma unroll
        for (int q = 0; q < 2; ++q) {
            const short* g = A + (size_t)(bm + q * 64 + srow) * K + skc;
            GLOAD_LDS16(g, &lds[0][q * 2048 + wv * 512]);
        }
        #pragma unroll
        for (int q = 0; q < 2; ++q) {
            const short* g = Bt + (size_t)(bn + q * 64 + srow) * K + skc;
            GLOAD_LDS16(g, &lds[0][4096 + q * 2048 + wv * 512]);
        }
    }
    __syncthreads();

    int cur = 0;
    const int lr = ln & 15;
    const int lk = (ln >> 4) * 8;

    for (int kt = 0; kt < 16; ++kt) {
        if (kt + 1 < 16) {
            int k0 = (kt + 1) << 5;
            #pragma unroll
            for (int q = 0; q < 2; ++q) {
                const short* g = A + (size_t)(bm + q * 64 + srow) * K + k0 + skc;
                GLOAD_LDS16(g, &lds[cur ^ 1][q * 2048 + wv * 512]);
            }
            #pragma unroll
            for (int q = 0; q < 2; ++q) {
                const short* g = Bt + (size_t)(bn + q * 64 + srow) * K + k0 + skc;
                GLOAD_LDS16(g, &lds[cur ^ 1][4096 + q * 2048 + wv * 512]);
            }
        }

        const short* As = &lds[cur][0];
        const short* Bs = &lds[cur][4096];
        short8 a[4], b[4];
        #pragma unroll
        for (int fi = 0; fi < 4; ++fi)
            a[fi] = *(const short8*)(As + (wm * 64 + fi * 16 + lr) * 32 + lk);
        #pragma unroll
        for (int fj = 0; fj < 4; ++fj)
            b[fj] = *(const short8*)(Bs + (wn * 64 + fj * 16 + lr) * 32 + lk);
        #pragma unroll
        for (int fi = 0; fi < 4; ++fi)
            #pragma unroll
            for (int fj = 0; fj < 4; ++fj)
                acc[fi][fj] = __builtin_amdgcn_mfma_f32_16x16x32_bf16(
                    a[fi], b[fj], acc[fi][fj], 0, 0, 0);

        __syncthreads();
        cur ^= 1;
    }

    unsigned short* Co = half ? opOut : apOut;
    const int rl0 = wm * 64 + (ln >> 4) * 4;
    const int cl0 = wn * 64 + lr;
    #pragma unroll
    for (int fi = 0; fi < 4; ++fi)
        #pragma unroll
        for (int r = 0; r < 4; ++r) {
            int rl = rl0 + fi * 16 + r;
            #pragma unroll
            for (int fj = 0; fj < 4; ++fj) {
                int cl = cl0 + fj * 16;
                float v = fmaxf(acc[fi][fj][r] + bias[bn + cl], 0.f);
                Co[(size_t)(bm + rl) * 128 + cl] = f2bf(v);
                if (cl < 101) tagf[rl * 101 + cl] = v;
            }
        }
    __syncthreads();

    if (t < 128) {
        float s[TAGS_];
        #pragma unroll
        for (int g = 0; g < TAGS_; ++g) s[g] = Btag[g];
        const float* rowp = &tagf[t * 101];
        for (int k = 0; k < HID_; ++k) {
            float x = rowp[k];
            #pragma unroll
            for (int g = 0; g < TAGS_; ++g) s[g] += x * Wtag[k * TAGS_ + g];
        }
        float* o = out_tag + (size_t)half * (BL_ * TAGS_) + (size_t)(bm + t) * TAGS_;
        #pragma unroll
        for (int g = 0; g < TAGS_; ++g) o[g] = s[g];
    }
}

// ---------------------------------------------------------------------------
// 4) Affine (K=128, single-stage LDS): affine = ap @ WtBi^T + bBi -> bf16
//    grid (128, 4). LDS layout: 4 ks-subtiles of [128][32].
// ---------------------------------------------------------------------------
__global__ __launch_bounds__(256) void affine_kernel(
    const short* __restrict__ ap, const short* __restrict__ WtBi,
    const float* __restrict__ bBi, unsigned short* __restrict__ affine)
{
    __shared__ __align__(16) short As[16384];
    __shared__ __align__(16) short Bs[16384];

    const int t  = threadIdx.x;
    const int wv = t >> 6;
    const int ln = t & 63;
    const int wm = wv >> 1;
    const int wn = wv & 1;
    const int bm = blockIdx.x * 128;
    const int bn = blockIdx.y * 128;

    const int rsub = ln >> 2;       // 0..15
    const int j8   = (ln & 3) * 8;  // k chunk within 32

    #pragma unroll
    for (int i = 0; i < 8; ++i) {
        int ks = i >> 1, hf = i & 1;
        int rloc = wv * 32 + hf * 16;
        const short* gA = ap + (size_t)(bm + rloc + rsub) * HIDP_ + ks * 32 + j8;
        GLOAD_LDS16(gA, &As[ks * 4096 + rloc * 32]);
        const short* gB = WtBi + (size_t)(bn + rloc + rsub) * HIDP_ + ks * 32 + j8;
        GLOAD_LDS16(gB, &Bs[ks * 4096 + rloc * 32]);
    }
    __syncthreads();

    const int lr = ln & 15;
    const int lk = (ln >> 4) * 8;
    f32x4 acc[4][4] = {};

    #pragma unroll
    for (int ks = 0; ks < 4; ++ks) {
        short8 a[4], b[4];
        #pragma unroll
        for (int fi = 0; fi < 4; ++fi)
            a[fi] = *(const short8*)(As + ks * 4096 + (wm * 64 + fi * 16 + lr) * 32 + lk);
        #pragma unroll
        for (int fj = 0; fj < 4; ++fj)
            b[fj] = *(const short8*)(Bs + ks * 4096 + (wn * 64 + fj * 16 + lr) * 32 + lk);
        #pragma unroll
        for (int fi = 0; fi < 4; ++fi)
            #pragma unroll
            for (int fj = 0; fj < 4; ++fj)
                acc[fi][fj] = __builtin_amdgcn_mfma_f32_16x16x32_bf16(
                    a[fi], b[fj], acc[fi][fj], 0, 0, 0);
    }

    const int row0 = bm + wm * 64 + (ln >> 4) * 4;
    const int col0 = bn + wn * 64 + lr;
    #pragma unroll
    for (int fi = 0; fi < 4; ++fi)
        #pragma unroll
        for (int r = 0; r < 4; ++r) {
            int row = row0 + fi * 16 + r;
            #pragma unroll
            for (int fj = 0; fj < 4; ++fj) {
                int col = col0 + fj * 16;
                affine[(size_t)row * NBI_ + col] = f2bf(acc[fi][fj][r] + bBi[col]);
            }
        }
}

// ---------------------------------------------------------------------------
// 5) Triplet (K=128, single-stage LDS): per batch b,
//    C[j, ip] = sum_h op[b,j,h] * affine[b, ip>>2, (ip&3)*128 + h] -> fp32 out
//    grid (2, 8, 64).
// ---------------------------------------------------------------------------
__global__ __launch_bounds__(256) void triplet_kernel(
    const short* __restrict__ op, const short* __restrict__ affine,
    float* __restrict__ out)
{
    __shared__ __align__(16) short As[16384];
    __shared__ __align__(16) short Bs[16384];

    const int t  = threadIdx.x;
    const int wv = t >> 6;
    const int ln = t & 63;
    const int wm = wv >> 1;
    const int wn = wv & 1;
    const int bm = blockIdx.x * 128;
    const int bn = blockIdx.y * 128;
    const int b  = blockIdx.z;

    const short* Ab = op     + (size_t)b * 256 * HIDP_;
    const short* Bb = affine + (size_t)b * 256 * NBI_;

    const int rsub = ln >> 2;
    const int j8   = (ln & 3) * 8;

    #pragma unroll
    for (int i = 0; i < 8; ++i) {
        int ks = i >> 1, hf = i & 1;
        int rloc = wv * 32 + hf * 16;
        const short* gA = Ab + (size_t)(bm + rloc + rsub) * HIDP_ + ks * 32 + j8;
        GLOAD_LDS16(gA, &As[ks * 4096 + rloc * 32]);
        int ip = bn + rloc + rsub;
        const short* gB = Bb + (size_t)(ip >> 2) * NBI_ + (ip & 3) * HIDP_ + ks * 32 + j8;
        GLOAD_LDS16(gB, &Bs[ks * 4096 + rloc * 32]);
    }
    __syncthreads();

    const int lr = ln & 15;
    const int lk = (ln >> 4) * 8;
    f32x4 acc[4][4] = {};

    #pragma unroll
    for (int ks = 0; ks < 4; ++ks) {
        short8 a[4], bf[4];
        #pragma unroll
        for (int fi = 0; fi < 4; ++fi)
            a[fi] = *(const short8*)(As + ks * 4096 + (wm * 64 + fi * 16 + lr) * 32 + lk);
        #pragma unroll
        for (int fj = 0; fj < 4; ++fj)
            bf[fj] = *(const short8*)(Bs + ks * 4096 + (wn * 64 + fj * 16 + lr) * 32 + lk);
        #pragma unroll
        for (int fi = 0; fi < 4; ++fi)
            #pragma unroll
            for (int fj = 0; fj < 4; ++fj)
                acc[fi][fj] = __builtin_amdgcn_mfma_f32_16x16x32_bf16(
                    a[fi], bf[fj], acc[fi][fj], 0, 0, 0);
    }

    float* O = out + (size_t)b * 256 * 1024;
    const int row0 = bm + wm * 64 + (ln >> 4) * 4;
    const int col0 = bn + wn * 64 + lr;
    #pragma unroll
    for (int fi = 0; fi < 4; ++fi)
        #pragma unroll
        for (int r = 0; r < 4; ++r) {
            int row = row0 + fi * 16 + r;
            #pragma unroll
            for (int fj = 0; fj < 4; ++fj)
                O[(size_t)row * 1024 + col0 + fj * 16] = acc[fi][fj][r];
        }
}

// ---------------------------------------------------------------------------
extern "C" void kernel_launch(void* const* d_in, const int* in_sizes, int n_in,
                              void* d_out, int out_size, void* d_ws, size_t ws_size,
                              hipStream_t stream)
{
    const float* bert     = (const float*)d_in[0];
    const int*   pos      = (const int*)  d_in[1];
    const float* W_reduc  = (const float*)d_in[2];
    const float* b_reduc  = (const float*)d_in[3];
    const float* W_ap     = (const float*)d_in[4];
    const float* b_ap     = (const float*)d_in[5];
    const float* W_op     = (const float*)d_in[6];
    const float* b_op     = (const float*)d_in[7];
    const float* W_ap_tag = (const float*)d_in[8];
    const float* b_ap_tag = (const float*)d_in[9];
    const float* W_op_tag = (const float*)d_in[10];
    const float* b_op_tag = (const float*)d_in[11];
    const float* W_bi     = (const float*)d_in[12];

    float* out = (float*)d_out;

    // Workspace layout (bytes; all 16B-aligned)
    char* ws = (char*)d_ws;
    unsigned short* pooled = (unsigned short*)ws; ws += (size_t)BL_ * D_ * 2;
    unsigned short* h      = (unsigned short*)ws; ws += (size_t)BL_ * REDP_ * 2;
    unsigned short* ap     = (unsigned short*)ws; ws += (size_t)BL_ * HIDP_ * 2;
    unsigned short* opv    = (unsigned short*)ws; ws += (size_t)BL_ * HIDP_ * 2;
    unsigned short* affine = (unsigned short*)ws; ws += (size_t)BL_ * NBI_ * 2;
    unsigned short* WtR    = (unsigned short*)ws; ws += (size_t)REDP_ * D_ * 2;
    unsigned short* WtAO   = (unsigned short*)ws; ws += (size_t)NAO_ * REDP_ * 2;
    unsigned short* WtBi   = (unsigned short*)ws; ws += (size_t)NBI_ * HIDP_ * 2;
    float* bR  = (float*)ws;  ws += REDP_ * 4;
    float* bAO = (float*)ws;  ws += NAO_ * 4;
    float* bBi = (float*)ws;  ws += NBI_ * 4;

    // 0+1) seg_mean + prep (one launch)
    front_kernel<<<SEG_BLOCKS + PREP_BLOCKS, 256, 0, stream>>>(
        bert, pos, pooled,
        W_reduc, b_reduc, W_ap, b_ap, W_op, b_op, W_bi,
        WtR, WtAO, WtBi, bR, bAO, bBi);

    // 2) h = relu(pooled @ W_reduc + b)  [16384,768] x [512,768]^T
    gemm1_kernel<<<dim3(BL_ / 128, REDP_ / 128), 256, 0, stream>>>(
        (const short*)pooled, (const short*)WtR, bR, h, BL_, REDP_, D_);

    // 3) ap|op = relu(h @ [W_ap|W_op] + b) + tag heads
    gemm23_tag_kernel<<<dim3(BL_ / 128, 2), 256, 0, stream>>>(
        (const short*)h, (const short*)WtAO, bAO, ap, opv,
        W_ap_tag, b_ap_tag, W_op_tag, b_op_tag, out);

    // 4) affine = ap @ W_bi[:100] + W_bi[100]  [16384,128] x [512,128]^T
    affine_kernel<<<dim3(BL_ / 128, NBI_ / 128), 256, 0, stream>>>(
        (const short*)ap, (const short*)WtBi, bBi, affine);

    // 5) triplet -> out[163840 : ]
    triplet_kernel<<<dim3(2, 8, B_), 256, 0, stream>>>(
        (const short*)opv, (const short*)affine, out + 2 * BL_ * TAGS_);
}